// Round 4
// baseline (340.494 us; speedup 1.0000x reference)
//
#include <hip/hip_runtime.h>

using u16 = unsigned short;
using u32 = unsigned int;

typedef __attribute__((ext_vector_type(8))) short short8;
typedef __attribute__((ext_vector_type(4))) float floatx4;

constexpr int TOKENS = 128;   // N (M dim of GEMMs)
constexpr int DM = 2560;      // D
constexpr int DI = 5120;      // DIN
constexpr int NS = 16;        // S
constexpr int NR = 160;       // R
constexpr int NP = 192;       // R + 2S

// ---- BIG workspace layout (floats): atomic-free split-K partials ----
constexpr size_t ND    = (size_t)TOKENS * DI;    // 655360
constexpr size_t XS_P  = 0;                       // 8 x ND   (xs partials; z aliases after E1)
constexpr size_t RES_P = XS_P + 8 * ND;           // 8 x ND   (res partials; oacc_p aliases after K5)
constexpr size_t U_OFF = RES_P + 8 * ND;          // ND
constexpr size_t DT_P  = U_OFF + ND;              // 5 x ND
constexpr size_t PRJ_P = DT_P + 5 * ND;           // 40 x 24576
constexpr size_t PRJ   = PRJ_P + 40 * (size_t)(TOKENS * NP);
constexpr size_t NEED  = PRJ + (size_t)(TOKENS * NP);   // ~15.4M floats (~62MB)

// ---- SMALL fallback layout (atomic split-K, r3-proven) ----
constexpr size_t S_XS  = 0;
constexpr size_t S_RES = S_XS + ND;
constexpr size_t S_U   = S_RES + ND;
constexpr size_t S_DT  = S_U + ND;
constexpr size_t S_PRJ = S_DT + ND;
constexpr size_t S_OAC = S_PRJ + (size_t)(TOKENS * NP);

__device__ __forceinline__ float bf2f(u16 h) {
  u32 u = ((u32)h) << 16;
  return __builtin_bit_cast(float, u);
}
__device__ __forceinline__ u16 f2bf(float f) {   // scalar fallback
  u32 u = __builtin_bit_cast(u32, f);
  u += 0x7FFFu + ((u >> 16) & 1u);   // RNE
  return (u16)(u >> 16);
}
// HW packed f32->bf16 (RNE), 1 instr per 2 elems
__device__ __forceinline__ u32 pk2(float a, float b) {
  u32 r;
  asm("v_cvt_pk_bf16_f32 %0, %1, %2" : "=v"(r) : "v"(a), "v"(b));
  return r;
}
__device__ __forceinline__ float ldsc(const void* p, size_t i, bool bf) {
  return bf ? bf2f(((const u16*)p)[i]) : ((const float*)p)[i];
}
// load 8 consecutive elements as packed bf16 (uint4); i multiple of 8
__device__ __forceinline__ uint4 ld8(const void* p, size_t i, bool bf) {
  if (bf) return *(const uint4*)((const u16*)p + i);
  const float4* f = (const float4*)((const float*)p + i);
  float4 a = f[0], b = f[1];
  return (uint4){pk2(a.x, a.y), pk2(a.z, a.w), pk2(b.x, b.y), pk2(b.z, b.w)};
}
// load 8 consecutive elements to f32
__device__ __forceinline__ void ld8f(const void* p, size_t i, bool bf, float* o) {
  if (bf) {
    uint4 v = *(const uint4*)((const u16*)p + i);
    const u16* h = (const u16*)&v;
#pragma unroll
    for (int e = 0; e < 8; e++) o[e] = bf2f(h[e]);
  } else {
    const float4* f = (const float4*)((const float*)p + i);
    float4 a = f[0], b = f[1];
    o[0] = a.x; o[1] = a.y; o[2] = a.z; o[3] = a.w;
    o[4] = b.x; o[5] = b.y; o[6] = b.z; o[7] = b.w;
  }
}

struct GemmP {
  const void* A; int lda; int a_ws;
  const void* B; const void* B2;
  float* C; float* C2;
  int ldb; int ldc;
  int ksteps;          // BK=32 steps per split
  int nx_half;         // blockIdx.x >= nx_half -> B2/C2
  int atomic;          // 1: atomicAdd into single C; 0: plain store into C + by*cstride
  size_t cstride;      // per-split partial-buffer stride (floats)
  const u32* probe;
};

// BM=128 BN=64 BK=32, 256 threads = 4 waves (2x2), wave tile 64x32 (4x2 mfma 16x16x32).
// LDS (12KB): row-major [row][32] u16 with 16B-block XOR swizzle
//   off(row,k) = row*32 + (((k>>3) ^ sw(row))<<3) + (k&7)
//   A: sw(m)=m&3 ; B stored transposed [n][k]: sw(n)=(n^(n>>3))&3
// A: 256 thr x 2 rows, b128 store + b128 read. B: 128 thr x 2 k-rows x 8 n,
// paired (k,k+1) b32 stores + b128 reads (2-way bank alias = free).
__global__ __launch_bounds__(256, 4) void gemm_k(GemmP p) {
  __shared__ __align__(16) u16 As[128 * 32];
  __shared__ __align__(16) u16 Bs[64 * 32];

  const bool bf = (p.probe[0] != 0u);
  const int tid = threadIdx.x;
  const int bx = blockIdx.x;
  const void* B = p.B; float* C = p.C;
  int nblk = bx;
  if (bx >= p.nx_half) { B = p.B2; C = p.C2; nblk = bx - p.nx_half; }
  const int n0 = nblk * 64;
  const int kstart = blockIdx.y * p.ksteps * 32;
  if (!p.atomic) C += blockIdx.y * p.cstride;

  const int wave = tid >> 6, lane = tid & 63;
  const int q = lane >> 4, l16 = lane & 15;
  const int wx = wave & 1, wy = wave >> 1;

  const bool a_f32 = p.a_ws || !bf;

  const int ac = tid & 3;               // A: k-block column (0..3)
  const int am0 = tid >> 2;             // A: row base (0..63), rows am0, am0+64
  const bool bact = tid < 128;          // B staged by waves 0,1
  const int bc = tid & 7, pr = (tid >> 3) & 15;
  const int bn8 = bc * 8, k2 = 2 * pr;  // 2 k-rows per active thread

  floatx4 acc[4][2];
#pragma unroll
  for (int mi = 0; mi < 4; mi++)
#pragma unroll
    for (int ni = 0; ni < 2; ni++) acc[mi][ni] = (floatx4){0.f, 0.f, 0.f, 0.f};

  auto load_tiles = [&](int ks, uint4* aO, uint4* bO) {
    const int kb = kstart + ks * 32;
#pragma unroll
    for (int pa = 0; pa < 2; pa++) {
      const int m = am0 + pa * 64;
      const size_t off = (size_t)m * p.lda + kb + ac * 8;
      if (!a_f32) {
        aO[pa] = *(const uint4*)((const u16*)p.A + off);
      } else {
        const float4* f = (const float4*)((const float*)p.A + off);
        float4 x0 = f[0], x1 = f[1];
        aO[pa] = (uint4){pk2(x0.x, x0.y), pk2(x0.z, x0.w),
                         pk2(x1.x, x1.y), pk2(x1.z, x1.w)};
      }
    }
    if (bact) {
      bO[0] = ld8(B, (size_t)(kb + k2) * p.ldb + n0 + bn8, bf);
      bO[1] = ld8(B, (size_t)(kb + k2 + 1) * p.ldb + n0 + bn8, bf);
    }
  };

  auto store_tiles = [&](const uint4* aO, const uint4* bO) {
#pragma unroll
    for (int pa = 0; pa < 2; pa++) {
      const int m = am0 + pa * 64;
      *(uint4*)&As[m * 32 + ((ac ^ (m & 3)) << 3)] = aO[pa];
    }
    if (bact) {
      const u16* lo = (const u16*)&bO[0];
      const u16* hi = (const u16*)&bO[1];
#pragma unroll
      for (int j = 0; j < 8; j++) {
        const int n = bn8 + j;
        const int blk = (k2 >> 3) ^ ((n ^ (n >> 3)) & 3);
        *(u32*)&Bs[n * 32 + (blk << 3) + (k2 & 7)] =
            (u32)lo[j] | ((u32)hi[j] << 16);
      }
    }
  };

  // per-lane fragment addressing
  const int swA = l16 & 3;
  const int arow = (wy * 64 + l16) * 32;
  const int ao = ((q ^ swA) << 3);
  int nrow[2], bo[2];
#pragma unroll
  for (int ni = 0; ni < 2; ni++) {
    const int n = wx * 32 + ni * 16 + l16;
    nrow[ni] = n * 32;
    bo[ni] = ((q ^ ((n ^ (n >> 3)) & 3)) << 3);
  }

  auto compute = [&]() {
    short8 a[4];
#pragma unroll
    for (int mi = 0; mi < 4; mi++)
      a[mi] = __builtin_bit_cast(short8,
          *(const uint4*)&As[arow + mi * 16 * 32 + ao]);
    short8 b[2];
#pragma unroll
    for (int ni = 0; ni < 2; ni++)
      b[ni] = __builtin_bit_cast(short8, *(const uint4*)&Bs[nrow[ni] + bo[ni]]);
#pragma unroll
    for (int mi = 0; mi < 4; mi++)
#pragma unroll
      for (int ni = 0; ni < 2; ni++)
        acc[mi][ni] = __builtin_amdgcn_mfma_f32_16x16x32_bf16(
            a[mi], b[ni], acc[mi][ni], 0, 0, 0);
  };

  // depth-2 pipeline over two named staging sets
  uint4 a0[2], b0[2], a1[2], b1[2];
  load_tiles(0, a0, b0);
  if (p.ksteps > 1) load_tiles(1, a1, b1);
  int ks = 0;
  for (;;) {
    __syncthreads();
    store_tiles(a0, b0);
    if (ks + 2 < p.ksteps) load_tiles(ks + 2, a0, b0);
    __syncthreads();
    compute();
    if (++ks == p.ksteps) break;

    __syncthreads();
    store_tiles(a1, b1);
    if (ks + 2 < p.ksteps) load_tiles(ks + 2, a1, b1);
    __syncthreads();
    compute();
    if (++ks == p.ksteps) break;
  }

  // epilogue: row = wy*64+mi*16+q*4+r, col = n0+wx*32+ni*16+l16
#pragma unroll
  for (int ni = 0; ni < 2; ni++) {
    const int col = n0 + wx * 32 + ni * 16 + l16;
#pragma unroll
    for (int mi = 0; mi < 4; mi++) {
      floatx4 v = acc[mi][ni];
#pragma unroll
      for (int r = 0; r < 4; r++) {
        const int row = wy * 64 + mi * 16 + q * 4 + r;
        if (p.atomic) atomicAdd(&C[(size_t)row * p.ldc + col], v[r]);
        else          C[(size_t)row * p.ldc + col] = v[r];
      }
    }
  }
}

// u = silu(conv_bias + w0*cs1 + w1*cs2 + w2*cs3 + w3*sum_j(xs_p[j])), 8/thread.
__global__ __launch_bounds__(256) void epi_u_k(
    const float* __restrict__ xs_p, int nred, size_t pstride,
    const void* __restrict__ cs1, const void* __restrict__ cs2,
    const void* __restrict__ cs3, const void* __restrict__ cw,
    const void* __restrict__ cb, float* __restrict__ u,
    const u32* __restrict__ probe) {
  const bool bf = (probe[0] != 0u);
  const int idx = blockIdx.x * 256 + threadIdx.x;
  const int n = idx / (DI / 8);
  const int d0 = (idx - n * (DI / 8)) * 8;
  const size_t nd = (size_t)n * DI + d0;
  float xv[8] = {0.f, 0.f, 0.f, 0.f, 0.f, 0.f, 0.f, 0.f};
  for (int j = 0; j < nred; j++) {
    const float4* f = (const float4*)(xs_p + j * pstride + nd);
    float4 a = f[0], b = f[1];
    xv[0] += a.x; xv[1] += a.y; xv[2] += a.z; xv[3] += a.w;
    xv[4] += b.x; xv[5] += b.y; xv[6] += b.z; xv[7] += b.w;
  }
  float c1[8], c2[8], c3[8], w0[8], w1[8], w2[8], w3[8], bb[8];
  ld8f(cs1, nd, bf, c1);
  ld8f(cs2, nd, bf, c2);
  ld8f(cs3, nd, bf, c3);
  ld8f(cw, (size_t)0 * DI + d0, bf, w0);
  ld8f(cw, (size_t)1 * DI + d0, bf, w1);
  ld8f(cw, (size_t)2 * DI + d0, bf, w2);
  ld8f(cw, (size_t)3 * DI + d0, bf, w3);
  ld8f(cb, d0, bf, bb);
  float o[8];
#pragma unroll
  for (int e = 0; e < 8; e++) {
    float cv = bb[e] + w0[e] * c1[e] + w1[e] * c2[e] + w2[e] * c3[e] +
               w3[e] * xv[e];
    o[e] = cv / (1.0f + __expf(-cv));
  }
  float4* uo = (float4*)(u + nd);
  uo[0] = (float4){o[0], o[1], o[2], o[3]};
  uo[1] = (float4){o[4], o[5], o[6], o[7]};
}

// tiny reduce: proj = sum_j proj_p[j]  (grid 96, 24576 elems)
__global__ __launch_bounds__(256) void rproj_k(const float* __restrict__ in,
                                               int nred, size_t pstride,
                                               float* __restrict__ out) {
  const int i = blockIdx.x * 256 + threadIdx.x;
  if (i < TOKENS * NP) {
    float s = 0.f;
    for (int j = 0; j < nred; j++) s += in[j * pstride + i];
    out[i] = s;
  }
}

// SSM scan + dt softplus (+ res & dt split-reduce) -> z = y * res
__global__ __launch_bounds__(256) void ssm_k(
    const void* __restrict__ sstate, const void* __restrict__ alog,
    const void* __restrict__ dparam, const void* __restrict__ dtb,
    const float* __restrict__ proj, const float* __restrict__ dt_p,
    int nred_d, size_t sd, const float* __restrict__ u,
    const float* __restrict__ res_p, int nred_r, size_t sr,
    float* __restrict__ z, const u32* __restrict__ probe) {
  const bool bf = (probe[0] != 0u);
  const int n = blockIdx.y;
  const int d = blockIdx.x * 256 + threadIdx.x;
  __shared__ float Bsh[NS], Csh[NS];
  if (threadIdx.x < NS)
    Bsh[threadIdx.x] = proj[(size_t)n * NP + NR + threadIdx.x];
  else if (threadIdx.x < 2 * NS)
    Csh[threadIdx.x - NS] = proj[(size_t)n * NP + NR + threadIdx.x];
  __syncthreads();
  const size_t nd = (size_t)n * DI + d;
  const float uv = u[nd];
  float rv = 0.f;
  for (int j = 0; j < nred_r; j++) rv += res_p[j * sr + nd];
  float sv = ldsc(dtb, d, bf);
  for (int j = 0; j < nred_d; j++) sv += dt_p[j * sd + nd];
  const float dtv = (sv > 20.0f) ? sv : log1pf(__expf(sv));  // softplus

  float stf[16], alf[16];
  if (bf) {
    u16 st[16], al[16];
    const uint4* sp = (const uint4*)((const u16*)sstate + nd * 16);
    *(uint4*)&st[0] = sp[0]; *(uint4*)&st[8] = sp[1];
    const uint4* ap = (const uint4*)((const u16*)alog + (size_t)d * 16);
    *(uint4*)&al[0] = ap[0]; *(uint4*)&al[8] = ap[1];
#pragma unroll
    for (int s = 0; s < 16; s++) { stf[s] = bf2f(st[s]); alf[s] = bf2f(al[s]); }
  } else {
    const float4* sp = (const float4*)((const float*)sstate + nd * 16);
    const float4* ap = (const float4*)((const float*)alog + (size_t)d * 16);
#pragma unroll
    for (int i = 0; i < 4; i++) {
      float4 s4 = sp[i], a4 = ap[i];
      stf[i * 4 + 0] = s4.x; stf[i * 4 + 1] = s4.y; stf[i * 4 + 2] = s4.z; stf[i * 4 + 3] = s4.w;
      alf[i * 4 + 0] = a4.x; alf[i * 4 + 1] = a4.y; alf[i * 4 + 2] = a4.z; alf[i * 4 + 3] = a4.w;
    }
  }
  float y = 0.f;
#pragma unroll
  for (int s = 0; s < 16; s++) {
    float Aa = -__expf(alf[s]);
    float dA = __expf(dtv * Aa);
    float h = dA * stf[s] + dtv * Bsh[s] * uv;
    y += h * Csh[s];
  }
  y += ldsc(dparam, d, bf) * uv;
  z[nd] = y * rv;
}

// output convert + oacc split-reduce, 8 elems/thread
__global__ __launch_bounds__(256) void cvt_k(const float* __restrict__ in,
                                             int nred, size_t pstride,
                                             void* __restrict__ out, int n,
                                             const u32* __restrict__ probe) {
  const bool bf = (probe[0] != 0u);
  const int i0 = (blockIdx.x * 256 + threadIdx.x) * 8;
  if (i0 + 8 <= n) {
    float o[8] = {0.f, 0.f, 0.f, 0.f, 0.f, 0.f, 0.f, 0.f};
    for (int j = 0; j < nred; j++) {
      const float4* f = (const float4*)(in + j * pstride + i0);
      float4 a = f[0], b = f[1];
      o[0] += a.x; o[1] += a.y; o[2] += a.z; o[3] += a.w;
      o[4] += b.x; o[5] += b.y; o[6] += b.z; o[7] += b.w;
    }
    if (bf) {
      uint4 v = {pk2(o[0], o[1]), pk2(o[2], o[3]), pk2(o[4], o[5]), pk2(o[6], o[7])};
      *(uint4*)((u16*)out + i0) = v;
    } else {
      float4* fo = (float4*)((float*)out + i0);
      fo[0] = (float4){o[0], o[1], o[2], o[3]};
      fo[1] = (float4){o[4], o[5], o[6], o[7]};
    }
  } else {
    for (int i = i0; i < n; i++) {
      float s = 0.f;
      for (int j = 0; j < nred; j++) s += in[j * pstride + i];
      if (bf) ((u16*)out)[i] = f2bf(s);
      else    ((float*)out)[i] = s;
    }
  }
}

extern "C" void kernel_launch(void* const* d_in, const int* in_sizes, int n_in,
                              void* d_out, int out_size, void* d_ws, size_t ws_size,
                              hipStream_t stream) {
  const void* x         = d_in[0];
  const void* cs1       = d_in[2];
  const void* cs2       = d_in[3];
  const void* cs3       = d_in[4];
  const void* ssm_state = d_in[5];
  const void* ssm_proj  = d_in[6];
  const void* mlp_proj  = d_in[7];
  const void* down_proj = d_in[8];
  const void* conv_w    = d_in[9];
  const void* conv_b    = d_in[10];
  const void* x_proj_w  = d_in[11];
  const void* dt_proj_w = d_in[12];
  const void* dt_proj_b = d_in[13];
  const void* A_log     = d_in[14];
  const void* D_param   = d_in[15];
  const u32*  probe     = (const u32*)A_log;

  float* ws = (float*)d_ws;
  const bool big = (ws_size / sizeof(float)) >= NEED;  // fixed per-session -> graph-stable

  if (big) {
    // ---- atomic-free path: plain-store partials + fused reduces, no memsets ----
    float* xs_p  = ws + XS_P;
    float* res_p = ws + RES_P;
    float* u     = ws + U_OFF;
    float* dt_p  = ws + DT_P;
    float* prj_p = ws + PRJ_P;
    float* prj   = ws + PRJ;
    float* z     = ws + XS_P;    // alias: xs_p dead after E1
    float* oac_p = ws + RES_P;   // alias: res_p dead after K5 (16*327680 == 8*655360)

    // K1: xs_p[j] / res_p[j] partials (split-K 8, 1280 blocks)
    {
      GemmP p{};
      p.A = x; p.lda = DM; p.a_ws = 0;
      p.B = ssm_proj; p.B2 = mlp_proj;
      p.C = xs_p; p.C2 = res_p;
      p.ldb = DI; p.ldc = DI;
      p.ksteps = 10; p.nx_half = 80; p.atomic = 0; p.cstride = ND;
      p.probe = probe;
      gemm_k<<<dim3(160, 8), 256, 0, stream>>>(p);
    }
    // E1: u = silu(conv(sum xs_p, states))
    epi_u_k<<<dim3(TOKENS * DI / 8 / 256), 256, 0, stream>>>(
        xs_p, 8, ND, cs1, cs2, cs3, conv_w, conv_b, u, probe);
    // K3: prj_p[j] partials (split-K 40, 120 blocks)
    {
      GemmP p{};
      p.A = u; p.lda = DI; p.a_ws = 1;
      p.B = x_proj_w; p.B2 = nullptr;
      p.C = prj_p; p.C2 = nullptr;
      p.ldb = NP; p.ldc = NP;
      p.ksteps = 4; p.nx_half = 1 << 30; p.atomic = 0;
      p.cstride = (size_t)TOKENS * NP;
      p.probe = probe;
      gemm_k<<<dim3(3, 40), 256, 0, stream>>>(p);
    }
    rproj_k<<<dim3((TOKENS * NP + 255) / 256), 256, 0, stream>>>(
        prj_p, 40, (size_t)TOKENS * NP, prj);
    // K4: dt_p[j] partials (split-K 5, 400 blocks)
    {
      GemmP p{};
      p.A = prj; p.lda = NP; p.a_ws = 1;
      p.B = dt_proj_w; p.B2 = nullptr;
      p.C = dt_p; p.C2 = nullptr;
      p.ldb = DI; p.ldc = DI;
      p.ksteps = 1; p.nx_half = 1 << 30; p.atomic = 0; p.cstride = ND;
      p.probe = probe;
      gemm_k<<<dim3(DI / 64, 5), 256, 0, stream>>>(p);
    }
    // K5: SSM scan (reduces res_p x8, dt_p x5) -> z
    ssm_k<<<dim3(DI / 256, TOKENS), 256, 0, stream>>>(
        ssm_state, A_log, D_param, dt_proj_b, prj, dt_p, 5, ND, u,
        res_p, 8, ND, z, probe);
    // K6: oac_p[j] partials (split-K 16, 640 blocks)
    {
      GemmP p{};
      p.A = z; p.lda = DI; p.a_ws = 1;
      p.B = down_proj; p.B2 = nullptr;
      p.C = oac_p; p.C2 = nullptr;
      p.ldb = DM; p.ldc = DM;
      p.ksteps = 10; p.nx_half = 1 << 30; p.atomic = 0;
      p.cstride = (size_t)TOKENS * DM;
      p.probe = probe;
      gemm_k<<<dim3(DM / 64, 16), 256, 0, stream>>>(p);
    }
    // K7: reduce 16 partials + convert
    cvt_k<<<dim3((out_size / 8 + 255) / 256), 256, 0, stream>>>(
        oac_p, 16, (size_t)TOKENS * DM, d_out, out_size, probe);
  } else {
    // ---- fallback: atomic split-K (r3-proven), memset-zeroed accumulators ----
    float* xs  = ws + S_XS;
    float* res = ws + S_RES;
    float* u   = ws + S_U;
    float* dt  = ws + S_DT;
    float* prj = ws + S_PRJ;
    float* oac = ws + S_OAC;
    float* z   = ws + S_XS;   // alias

    hipMemsetAsync(xs,  0, ND * sizeof(float), stream);
    hipMemsetAsync(res, 0, ND * sizeof(float), stream);
    hipMemsetAsync(dt,  0, ND * sizeof(float), stream);
    hipMemsetAsync(prj, 0, (size_t)TOKENS * NP * sizeof(float), stream);
    hipMemsetAsync(oac, 0, (size_t)TOKENS * DM * sizeof(float), stream);

    {
      GemmP p{};
      p.A = x; p.lda = DM; p.a_ws = 0;
      p.B = ssm_proj; p.B2 = mlp_proj;
      p.C = xs; p.C2 = res;
      p.ldb = DI; p.ldc = DI;
      p.ksteps = 10; p.nx_half = 80; p.atomic = 1; p.cstride = 0;
      p.probe = probe;
      gemm_k<<<dim3(160, 8), 256, 0, stream>>>(p);
    }
    epi_u_k<<<dim3(TOKENS * DI / 8 / 256), 256, 0, stream>>>(
        xs, 1, 0, cs1, cs2, cs3, conv_w, conv_b, u, probe);
    {
      GemmP p{};
      p.A = u; p.lda = DI; p.a_ws = 1;
      p.B = x_proj_w; p.B2 = nullptr;
      p.C = prj; p.C2 = nullptr;
      p.ldb = NP; p.ldc = NP;
      p.ksteps = 4; p.nx_half = 1 << 30; p.atomic = 1; p.cstride = 0;
      p.probe = probe;
      gemm_k<<<dim3(3, 40), 256, 0, stream>>>(p);
    }
    {
      GemmP p{};
      p.A = prj; p.lda = NP; p.a_ws = 1;
      p.B = dt_proj_w; p.B2 = nullptr;
      p.C = dt; p.C2 = nullptr;
      p.ldb = DI; p.ldc = DI;
      p.ksteps = 1; p.nx_half = 1 << 30; p.atomic = 1; p.cstride = 0;
      p.probe = probe;
      gemm_k<<<dim3(DI / 64, 5), 256, 0, stream>>>(p);
    }
    ssm_k<<<dim3(DI / 256, TOKENS), 256, 0, stream>>>(
        ssm_state, A_log, D_param, dt_proj_b, prj, dt, 1, 0, u,
        res, 1, 0, z, probe);
    {
      GemmP p{};
      p.A = z; p.lda = DI; p.a_ws = 1;
      p.B = down_proj; p.B2 = nullptr;
      p.C = oac; p.C2 = nullptr;
      p.ldb = DM; p.ldc = DM;
      p.ksteps = 10; p.nx_half = 1 << 30; p.atomic = 1; p.cstride = 0;
      p.probe = probe;
      gemm_k<<<dim3(DM / 64, 16), 256, 0, stream>>>(p);
    }
    cvt_k<<<dim3((out_size / 8 + 255) / 256), 256, 0, stream>>>(
        oac, 1, 0, d_out, out_size, probe);
  }
}

// Round 6
// 314.273 us; speedup vs baseline: 1.0834x; 1.0834x over previous
//
#include <hip/hip_runtime.h>

using u16 = unsigned short;
using u32 = unsigned int;

typedef __attribute__((ext_vector_type(8))) short short8;
typedef __attribute__((ext_vector_type(4))) float floatx4;

constexpr int TOKENS = 128;   // N (M dim of GEMMs)
constexpr int DM = 2560;      // D
constexpr int DI = 5120;      // DIN
constexpr int NS = 16;        // S
constexpr int NR = 160;       // R
constexpr int NP = 192;       // R + 2S

// ---- BIG workspace layout (floats): atomic-free split-K partials ----
constexpr size_t ND    = (size_t)TOKENS * DI;    // 655360
constexpr size_t XS_P  = 0;                       // 5 x ND (xs partials; z aliases after E1)
constexpr size_t RES_P = XS_P + 5 * ND;           // 5 x ND (res partials; oac_p aliases after K5)
constexpr size_t U_OFF = RES_P + 5 * ND;          // ND
constexpr size_t DT_P  = U_OFF + ND;              // 5 x ND
constexpr size_t PRJ_P = DT_P + 5 * ND;           // 40 x 24576
constexpr size_t PRJ   = PRJ_P + 40 * (size_t)(TOKENS * NP);
constexpr size_t NEED  = PRJ + (size_t)(TOKENS * NP);   // ~11.5M floats (~46MB)

// ---- SMALL fallback layout (atomic split-K) ----
constexpr size_t S_XS  = 0;
constexpr size_t S_RES = S_XS + ND;
constexpr size_t S_U   = S_RES + ND;
constexpr size_t S_DT  = S_U + ND;
constexpr size_t S_PRJ = S_DT + ND;
constexpr size_t S_OAC = S_PRJ + (size_t)(TOKENS * NP);

__device__ __forceinline__ float bf2f(u16 h) {
  u32 u = ((u32)h) << 16;
  return __builtin_bit_cast(float, u);
}
__device__ __forceinline__ u16 f2bf(float f) {   // scalar fallback
  u32 u = __builtin_bit_cast(u32, f);
  u += 0x7FFFu + ((u >> 16) & 1u);   // RNE
  return (u16)(u >> 16);
}
// HW packed f32->bf16 (RNE): lo half <- a, hi half <- b
__device__ __forceinline__ u32 pk2(float a, float b) {
  u32 r;
  asm("v_cvt_pk_bf16_f32 %0, %1, %2" : "=v"(r) : "v"(a), "v"(b));
  return r;
}
// 8 f32 (bit-cast in 2 uint4) -> 8 packed bf16
__device__ __forceinline__ uint4 pack8(uint4 lo, uint4 hi) {
  float4 a = __builtin_bit_cast(float4, lo), b = __builtin_bit_cast(float4, hi);
  return (uint4){pk2(a.x, a.y), pk2(a.z, a.w), pk2(b.x, b.y), pk2(b.z, b.w)};
}
__device__ __forceinline__ float ldsc(const void* p, size_t i, bool bf) {
  return bf ? bf2f(((const u16*)p)[i]) : ((const float*)p)[i];
}
// load 8 consecutive elements to f32
__device__ __forceinline__ void ld8f(const void* p, size_t i, bool bf, float* o) {
  if (bf) {
    uint4 v = *(const uint4*)((const u16*)p + i);
    const u16* h = (const u16*)&v;
#pragma unroll
    for (int e = 0; e < 8; e++) o[e] = bf2f(h[e]);
  } else {
    const float4* f = (const float4*)((const float*)p + i);
    float4 a = f[0], b = f[1];
    o[0] = a.x; o[1] = a.y; o[2] = a.z; o[3] = a.w;
    o[4] = b.x; o[5] = b.y; o[6] = b.z; o[7] = b.w;
  }
}

struct GemmP {
  const void* A; int lda; int a_ws;
  const void* B; const void* B2;
  float* C; float* C2;
  int ldb; int ldc;
  int ksteps;          // BK=32 steps per split
  int nx_half;         // blockIdx.x >= nx_half -> B2/C2
  int atomic;          // 1: atomicAdd into single C; 0: plain store into C + by*cstride
  size_t cstride;      // per-split partial-buffer stride (floats)
  const u32* probe;
};

// BM=128 BN=64 BK=32, 256 threads = 4 waves (2x2), wave tile 64x32.
// DOUBLE-BUFFERED LDS + raw s_barrier (ONE per K-step) + counted vmcnt:
//  - global loads fetch RAW bits to regs (no cvt at load -> no forced drain);
//    cvt f32->bf16 happens at ds_write time, so the compiler's auto-wait there
//    is a COUNTED vmcnt (younger prefetch batch stays in flight across barriers).
//  - write(t) overwrites buf read at compute(t-2); barrier(t-1) separates them.
//  - manual "s_waitcnt lgkmcnt(0)" + sched_barrier before each s_barrier makes
//    this wave's ds_writes visible (rule: no compiler fence with raw barrier).
// LDS swizzle (r3/r4-verified): off(row,k) = row*32 + (((k>>3)^sw)<<3) + (k&7),
//   A: sw = m&3 ; B stored transposed [n][k]: sw = (n^(n>>3))&3.
__global__ __launch_bounds__(256, 3) void gemm_k(GemmP p) {
  __shared__ __align__(16) u16 As[2 * 128 * 32];   // 16KB
  __shared__ __align__(16) u16 Bs[2 * 64 * 32];    //  8KB

  const bool bf = (p.probe[0] != 0u);
  const int tid = threadIdx.x;
  const int bx = blockIdx.x;
  const void* B = p.B; float* C = p.C;
  int nblk = bx;
  if (bx >= p.nx_half) { B = p.B2; C = p.C2; nblk = bx - p.nx_half; }
  const int n0 = nblk * 64;
  const int kstart = blockIdx.y * p.ksteps * 32;
  if (!p.atomic) C += blockIdx.y * p.cstride;

  const int wave = tid >> 6, lane = tid & 63;
  const int q = lane >> 4, l16 = lane & 15;
  const int wx = wave & 1, wy = wave >> 1;

  const bool a_f32 = p.a_ws || !bf;

  const int ac = tid & 3;               // A: k-octet (0..3)
  const int am0 = tid >> 2;             // A: row base (0..63); rows am0, am0+64
  const bool bact = tid < 128;          // B staged by waves 0,1
  const int bc = tid & 7, pr = (tid >> 3) & 15;
  const int bn8 = bc * 8, k2 = 2 * pr;  // 2 k-rows per active thread

  floatx4 acc[4][2];
#pragma unroll
  for (int mi = 0; mi < 4; mi++)
#pragma unroll
    for (int ni = 0; ni < 2; ni++) acc[mi][ni] = (floatx4){0.f, 0.f, 0.f, 0.f};

  // raw-bit staging: f32 path uses ra[0..3]/rb[0..3], bf16 path ra[0..1]/rb[0..1]
  auto load_tiles = [&](int ks, uint4* ra, uint4* rb) {
    const int kb = kstart + ks * 32;
    if (!a_f32) {
      ra[0] = *(const uint4*)((const u16*)p.A + (size_t)am0 * p.lda + kb + ac * 8);
      ra[1] = *(const uint4*)((const u16*)p.A + (size_t)(am0 + 64) * p.lda + kb + ac * 8);
    } else {
      const float* Af = (const float*)p.A;
      const float4* f0 = (const float4*)(Af + (size_t)am0 * p.lda + kb + ac * 8);
      const float4* f1 = (const float4*)(Af + (size_t)(am0 + 64) * p.lda + kb + ac * 8);
      ra[0] = __builtin_bit_cast(uint4, f0[0]); ra[1] = __builtin_bit_cast(uint4, f0[1]);
      ra[2] = __builtin_bit_cast(uint4, f1[0]); ra[3] = __builtin_bit_cast(uint4, f1[1]);
    }
    if (bact) {
      if (bf) {
        rb[0] = *(const uint4*)((const u16*)B + (size_t)(kb + k2) * p.ldb + n0 + bn8);
        rb[1] = *(const uint4*)((const u16*)B + (size_t)(kb + k2 + 1) * p.ldb + n0 + bn8);
      } else {
        const float* Bf = (const float*)B;
        const float4* g0 = (const float4*)(Bf + (size_t)(kb + k2) * p.ldb + n0 + bn8);
        const float4* g1 = (const float4*)(Bf + (size_t)(kb + k2 + 1) * p.ldb + n0 + bn8);
        rb[0] = __builtin_bit_cast(uint4, g0[0]); rb[1] = __builtin_bit_cast(uint4, g0[1]);
        rb[2] = __builtin_bit_cast(uint4, g1[0]); rb[3] = __builtin_bit_cast(uint4, g1[1]);
      }
    }
  };

  auto store_tiles = [&](int b, const uint4* ra, const uint4* rb) {
    u16* Ab = &As[b * 4096];
    u16* Bb = &Bs[b * 2048];
    uint4 w0, w1;
    if (!a_f32) { w0 = ra[0]; w1 = ra[1]; }
    else        { w0 = pack8(ra[0], ra[1]); w1 = pack8(ra[2], ra[3]); }
    *(uint4*)&Ab[am0 * 32 + ((ac ^ (am0 & 3)) << 3)] = w0;
    const int m1 = am0 + 64;
    *(uint4*)&Ab[m1 * 32 + ((ac ^ (m1 & 3)) << 3)] = w1;
    if (bact) {
      u32 pk[8];
      if (bf) {
        const u16* lo = (const u16*)&rb[0];
        const u16* hi = (const u16*)&rb[1];
#pragma unroll
        for (int j = 0; j < 8; j++) pk[j] = (u32)lo[j] | ((u32)hi[j] << 16);
      } else {
        const float* lo = (const float*)&rb[0];   // rb[0..1]: 8 floats, row k2
        const float* hi = (const float*)&rb[2];   // rb[2..3]: row k2+1
#pragma unroll
        for (int j = 0; j < 8; j++) pk[j] = pk2(lo[j], hi[j]);
      }
#pragma unroll
      for (int j = 0; j < 8; j++) {
        const int n = bn8 + j;
        const int blk = (k2 >> 3) ^ ((n ^ (n >> 3)) & 3);
        *(u32*)&Bb[n * 32 + (blk << 3) + (k2 & 7)] = pk[j];
      }
    }
  };

  // per-lane fragment addressing (r4-verified swizzle)
  const int swA = l16 & 3;
  const int arow = (wy * 64 + l16) * 32;
  const int ao = ((q ^ swA) << 3);
  int nrow[2], bo[2];
#pragma unroll
  for (int ni = 0; ni < 2; ni++) {
    const int n = wx * 32 + ni * 16 + l16;
    nrow[ni] = n * 32;
    bo[ni] = ((q ^ ((n ^ (n >> 3)) & 3)) << 3);
  }

  auto compute = [&](int b) {
    const u16* Ab = &As[b * 4096];
    const u16* Bb = &Bs[b * 2048];
    short8 a[4];
#pragma unroll
    for (int mi = 0; mi < 4; mi++)
      a[mi] = __builtin_bit_cast(short8, *(const uint4*)&Ab[arow + mi * 512 + ao]);
    short8 bb[2];
#pragma unroll
    for (int ni = 0; ni < 2; ni++)
      bb[ni] = __builtin_bit_cast(short8, *(const uint4*)&Bb[nrow[ni] + bo[ni]]);
#pragma unroll
    for (int mi = 0; mi < 4; mi++)
#pragma unroll
      for (int ni = 0; ni < 2; ni++)
        acc[mi][ni] = __builtin_amdgcn_mfma_f32_16x16x32_bf16(
            a[mi], bb[ni], acc[mi][ni], 0, 0, 0);
  };

#define FENCE_BAR()                                        \
  asm volatile("s_waitcnt lgkmcnt(0)" ::: "memory");       \
  __builtin_amdgcn_sched_barrier(0);                       \
  __builtin_amdgcn_s_barrier()

  uint4 ra0[4], rb0[4], ra1[4], rb1[4];
  load_tiles(0, ra0, rb0);
  if (p.ksteps > 1) load_tiles(1, ra1, rb1);
  int t = 0;
  for (;;) {
    store_tiles(0, ra0, rb0);                       // counted vmcnt here
    if (t + 2 < p.ksteps) load_tiles(t + 2, ra0, rb0);
    FENCE_BAR();
    compute(0);
    if (++t == p.ksteps) break;

    store_tiles(1, ra1, rb1);
    if (t + 2 < p.ksteps) load_tiles(t + 2, ra1, rb1);
    FENCE_BAR();
    compute(1);
    if (++t == p.ksteps) break;
  }
#undef FENCE_BAR

  // epilogue: row = wy*64+mi*16+q*4+r, col = n0+wx*32+ni*16+l16
#pragma unroll
  for (int ni = 0; ni < 2; ni++) {
    const int col = n0 + wx * 32 + ni * 16 + l16;
#pragma unroll
    for (int mi = 0; mi < 4; mi++) {
      floatx4 v = acc[mi][ni];
#pragma unroll
      for (int r = 0; r < 4; r++) {
        const int row = wy * 64 + mi * 16 + q * 4 + r;
        if (p.atomic) atomicAdd(&C[(size_t)row * p.ldc + col], v[r]);
        else          C[(size_t)row * p.ldc + col] = v[r];
      }
    }
  }
}

// u = silu(conv_bias + w0*cs1 + w1*cs2 + w2*cs3 + w3*sum_j(xs_p[j])), 8/thread.
__global__ __launch_bounds__(256) void epi_u_k(
    const float* __restrict__ xs_p, int nred, size_t pstride,
    const void* __restrict__ cs1, const void* __restrict__ cs2,
    const void* __restrict__ cs3, const void* __restrict__ cw,
    const void* __restrict__ cb, float* __restrict__ u,
    const u32* __restrict__ probe) {
  const bool bf = (probe[0] != 0u);
  const int idx = blockIdx.x * 256 + threadIdx.x;
  const int n = idx / (DI / 8);
  const int d0 = (idx - n * (DI / 8)) * 8;
  const size_t nd = (size_t)n * DI + d0;
  float xv[8] = {0.f, 0.f, 0.f, 0.f, 0.f, 0.f, 0.f, 0.f};
  for (int j = 0; j < nred; j++) {
    const float4* f = (const float4*)(xs_p + j * pstride + nd);
    float4 a = f[0], b = f[1];
    xv[0] += a.x; xv[1] += a.y; xv[2] += a.z; xv[3] += a.w;
    xv[4] += b.x; xv[5] += b.y; xv[6] += b.z; xv[7] += b.w;
  }
  float c1[8], c2[8], c3[8], w0[8], w1[8], w2[8], w3[8], bb[8];
  ld8f(cs1, nd, bf, c1);
  ld8f(cs2, nd, bf, c2);
  ld8f(cs3, nd, bf, c3);
  ld8f(cw, (size_t)0 * DI + d0, bf, w0);
  ld8f(cw, (size_t)1 * DI + d0, bf, w1);
  ld8f(cw, (size_t)2 * DI + d0, bf, w2);
  ld8f(cw, (size_t)3 * DI + d0, bf, w3);
  ld8f(cb, d0, bf, bb);
  float o[8];
#pragma unroll
  for (int e = 0; e < 8; e++) {
    float cv = bb[e] + w0[e] * c1[e] + w1[e] * c2[e] + w2[e] * c3[e] +
               w3[e] * xv[e];
    o[e] = cv / (1.0f + __expf(-cv));
  }
  float4* uo = (float4*)(u + nd);
  uo[0] = (float4){o[0], o[1], o[2], o[3]};
  uo[1] = (float4){o[4], o[5], o[6], o[7]};
}

// tiny reduce: proj = sum_j proj_p[j]
__global__ __launch_bounds__(256) void rproj_k(const float* __restrict__ in,
                                               int nred, size_t pstride,
                                               float* __restrict__ out) {
  const int i = blockIdx.x * 256 + threadIdx.x;
  if (i < TOKENS * NP) {
    float s = 0.f;
    for (int j = 0; j < nred; j++) s += in[j * pstride + i];
    out[i] = s;
  }
}

// SSM scan + dt softplus (+ res & dt split-reduce) -> z = y * res
__global__ __launch_bounds__(256) void ssm_k(
    const void* __restrict__ sstate, const void* __restrict__ alog,
    const void* __restrict__ dparam, const void* __restrict__ dtb,
    const float* __restrict__ proj, const float* __restrict__ dt_p,
    int nred_d, size_t sd, const float* __restrict__ u,
    const float* __restrict__ res_p, int nred_r, size_t sr,
    float* __restrict__ z, const u32* __restrict__ probe) {
  const bool bf = (probe[0] != 0u);
  const int n = blockIdx.y;
  const int d = blockIdx.x * 256 + threadIdx.x;
  __shared__ float Bsh[NS], Csh[NS];
  if (threadIdx.x < NS)
    Bsh[threadIdx.x] = proj[(size_t)n * NP + NR + threadIdx.x];
  else if (threadIdx.x < 2 * NS)
    Csh[threadIdx.x - NS] = proj[(size_t)n * NP + NR + threadIdx.x];
  __syncthreads();
  const size_t nd = (size_t)n * DI + d;
  const float uv = u[nd];
  float rv = 0.f;
  for (int j = 0; j < nred_r; j++) rv += res_p[j * sr + nd];
  float sv = ldsc(dtb, d, bf);
  for (int j = 0; j < nred_d; j++) sv += dt_p[j * sd + nd];
  const float dtv = (sv > 20.0f) ? sv : log1pf(__expf(sv));  // softplus

  float stf[16], alf[16];
  if (bf) {
    u16 st[16], al[16];
    const uint4* sp = (const uint4*)((const u16*)sstate + nd * 16);
    *(uint4*)&st[0] = sp[0]; *(uint4*)&st[8] = sp[1];
    const uint4* ap = (const uint4*)((const u16*)alog + (size_t)d * 16);
    *(uint4*)&al[0] = ap[0]; *(uint4*)&al[8] = ap[1];
#pragma unroll
    for (int s = 0; s < 16; s++) { stf[s] = bf2f(st[s]); alf[s] = bf2f(al[s]); }
  } else {
    const float4* sp = (const float4*)((const float*)sstate + nd * 16);
    const float4* ap = (const float4*)((const float*)alog + (size_t)d * 16);
#pragma unroll
    for (int i = 0; i < 4; i++) {
      float4 s4 = sp[i], a4 = ap[i];
      stf[i * 4 + 0] = s4.x; stf[i * 4 + 1] = s4.y; stf[i * 4 + 2] = s4.z; stf[i * 4 + 3] = s4.w;
      alf[i * 4 + 0] = a4.x; alf[i * 4 + 1] = a4.y; alf[i * 4 + 2] = a4.z; alf[i * 4 + 3] = a4.w;
    }
  }
  float y = 0.f;
#pragma unroll
  for (int s = 0; s < 16; s++) {
    float Aa = -__expf(alf[s]);
    float dA = __expf(dtv * Aa);
    float h = dA * stf[s] + dtv * Bsh[s] * uv;
    y += h * Csh[s];
  }
  y += ldsc(dparam, d, bf) * uv;
  z[nd] = y * rv;
}

// output convert + oacc split-reduce, 8 elems/thread
__global__ __launch_bounds__(256) void cvt_k(const float* __restrict__ in,
                                             int nred, size_t pstride,
                                             void* __restrict__ out, int n,
                                             const u32* __restrict__ probe) {
  const bool bf = (probe[0] != 0u);
  const int i0 = (blockIdx.x * 256 + threadIdx.x) * 8;
  if (i0 + 8 <= n) {
    float o[8] = {0.f, 0.f, 0.f, 0.f, 0.f, 0.f, 0.f, 0.f};
    for (int j = 0; j < nred; j++) {
      const float4* f = (const float4*)(in + j * pstride + i0);
      float4 a = f[0], b = f[1];
      o[0] += a.x; o[1] += a.y; o[2] += a.z; o[3] += a.w;
      o[4] += b.x; o[5] += b.y; o[6] += b.z; o[7] += b.w;
    }
    if (bf) {
      uint4 v = {pk2(o[0], o[1]), pk2(o[2], o[3]), pk2(o[4], o[5]), pk2(o[6], o[7])};
      *(uint4*)((u16*)out + i0) = v;
    } else {
      float4* fo = (float4*)((float*)out + i0);
      fo[0] = (float4){o[0], o[1], o[2], o[3]};
      fo[1] = (float4){o[4], o[5], o[6], o[7]};
    }
  } else {
    for (int i = i0; i < n; i++) {
      float s = 0.f;
      for (int j = 0; j < nred; j++) s += in[j * pstride + i];
      if (bf) ((u16*)out)[i] = f2bf(s);
      else    ((float*)out)[i] = s;
    }
  }
}

extern "C" void kernel_launch(void* const* d_in, const int* in_sizes, int n_in,
                              void* d_out, int out_size, void* d_ws, size_t ws_size,
                              hipStream_t stream) {
  const void* x         = d_in[0];
  const void* cs1       = d_in[2];
  const void* cs2       = d_in[3];
  const void* cs3       = d_in[4];
  const void* ssm_state = d_in[5];
  const void* ssm_proj  = d_in[6];
  const void* mlp_proj  = d_in[7];
  const void* down_proj = d_in[8];
  const void* conv_w    = d_in[9];
  const void* conv_b    = d_in[10];
  const void* x_proj_w  = d_in[11];
  const void* dt_proj_w = d_in[12];
  const void* dt_proj_b = d_in[13];
  const void* A_log     = d_in[14];
  const void* D_param   = d_in[15];
  const u32*  probe     = (const u32*)A_log;

  float* ws = (float*)d_ws;
  const bool big = (ws_size / sizeof(float)) >= NEED;

  if (big) {
    float* xs_p  = ws + XS_P;
    float* res_p = ws + RES_P;
    float* u     = ws + U_OFF;
    float* dt_p  = ws + DT_P;
    float* prj_p = ws + PRJ_P;
    float* prj   = ws + PRJ;
    float* z     = ws + XS_P;    // alias: xs_p dead after E1
    float* oac_p = ws + RES_P;   // alias: res_p dead after K5 (10*327680 == 5*655360)

    // K1: xs_p / res_p partials (split-K 5, 800 blocks x 16 steps)
    {
      GemmP p{};
      p.A = x; p.lda = DM; p.a_ws = 0;
      p.B = ssm_proj; p.B2 = mlp_proj;
      p.C = xs_p; p.C2 = res_p;
      p.ldb = DI; p.ldc = DI;
      p.ksteps = 16; p.nx_half = 80; p.atomic = 0; p.cstride = ND;
      p.probe = probe;
      gemm_k<<<dim3(160, 5), 256, 0, stream>>>(p);
    }
    // E1: u = silu(conv(sum xs_p, states))
    epi_u_k<<<dim3(TOKENS * DI / 8 / 256), 256, 0, stream>>>(
        xs_p, 5, ND, cs1, cs2, cs3, conv_w, conv_b, u, probe);
    // K3: prj_p partials (split-K 40, 120 blocks x 4 steps)
    {
      GemmP p{};
      p.A = u; p.lda = DI; p.a_ws = 1;
      p.B = x_proj_w; p.B2 = nullptr;
      p.C = prj_p; p.C2 = nullptr;
      p.ldb = NP; p.ldc = NP;
      p.ksteps = 4; p.nx_half = 1 << 30; p.atomic = 0;
      p.cstride = (size_t)TOKENS * NP;
      p.probe = probe;
      gemm_k<<<dim3(3, 40), 256, 0, stream>>>(p);
    }
    rproj_k<<<dim3((TOKENS * NP + 255) / 256), 256, 0, stream>>>(
        prj_p, 40, (size_t)TOKENS * NP, prj);
    // K4: dt_p partials (split-K 5, 400 blocks x 1 step)
    {
      GemmP p{};
      p.A = prj; p.lda = NP; p.a_ws = 1;
      p.B = dt_proj_w; p.B2 = nullptr;
      p.C = dt_p; p.C2 = nullptr;
      p.ldb = DI; p.ldc = DI;
      p.ksteps = 1; p.nx_half = 1 << 30; p.atomic = 0; p.cstride = ND;
      p.probe = probe;
      gemm_k<<<dim3(DI / 64, 5), 256, 0, stream>>>(p);
    }
    // K5: SSM scan (reduces res_p x5, dt_p x5) -> z
    ssm_k<<<dim3(DI / 256, TOKENS), 256, 0, stream>>>(
        ssm_state, A_log, D_param, dt_proj_b, prj, dt_p, 5, ND, u,
        res_p, 5, ND, z, probe);
    // K6: oac_p partials (split-K 10, 400 blocks x 16 steps)
    {
      GemmP p{};
      p.A = z; p.lda = DI; p.a_ws = 1;
      p.B = down_proj; p.B2 = nullptr;
      p.C = oac_p; p.C2 = nullptr;
      p.ldb = DM; p.ldc = DM;
      p.ksteps = 16; p.nx_half = 1 << 30; p.atomic = 0;
      p.cstride = (size_t)TOKENS * DM;
      p.probe = probe;
      gemm_k<<<dim3(DM / 64, 10), 256, 0, stream>>>(p);
    }
    // K7: reduce 10 partials + convert
    cvt_k<<<dim3((out_size / 8 + 255) / 256), 256, 0, stream>>>(
        oac_p, 10, (size_t)TOKENS * DM, d_out, out_size, probe);
  } else {
    // fallback: atomic split-K + memsets
    float* xs  = ws + S_XS;
    float* res = ws + S_RES;
    float* u   = ws + S_U;
    float* dt  = ws + S_DT;
    float* prj = ws + S_PRJ;
    float* oac = ws + S_OAC;
    float* z   = ws + S_XS;   // alias

    hipMemsetAsync(xs,  0, ND * sizeof(float), stream);
    hipMemsetAsync(res, 0, ND * sizeof(float), stream);
    hipMemsetAsync(dt,  0, ND * sizeof(float), stream);
    hipMemsetAsync(prj, 0, (size_t)TOKENS * NP * sizeof(float), stream);
    hipMemsetAsync(oac, 0, (size_t)TOKENS * DM * sizeof(float), stream);

    {
      GemmP p{};
      p.A = x; p.lda = DM; p.a_ws = 0;
      p.B = ssm_proj; p.B2 = mlp_proj;
      p.C = xs; p.C2 = res;
      p.ldb = DI; p.ldc = DI;
      p.ksteps = 10; p.nx_half = 80; p.atomic = 1; p.cstride = 0;
      p.probe = probe;
      gemm_k<<<dim3(160, 8), 256, 0, stream>>>(p);
    }
    epi_u_k<<<dim3(TOKENS * DI / 8 / 256), 256, 0, stream>>>(
        xs, 1, 0, cs1, cs2, cs3, conv_w, conv_b, u, probe);
    {
      GemmP p{};
      p.A = u; p.lda = DI; p.a_ws = 1;
      p.B = x_proj_w; p.B2 = nullptr;
      p.C = prj; p.C2 = nullptr;
      p.ldb = NP; p.ldc = NP;
      p.ksteps = 4; p.nx_half = 1 << 30; p.atomic = 1; p.cstride = 0;
      p.probe = probe;
      gemm_k<<<dim3(3, 40), 256, 0, stream>>>(p);
    }
    {
      GemmP p{};
      p.A = prj; p.lda = NP; p.a_ws = 1;
      p.B = dt_proj_w; p.B2 = nullptr;
      p.C = dt; p.C2 = nullptr;
      p.ldb = DI; p.ldc = DI;
      p.ksteps = 1; p.nx_half = 1 << 30; p.atomic = 1; p.cstride = 0;
      p.probe = probe;
      gemm_k<<<dim3(DI / 64, 5), 256, 0, stream>>>(p);
    }
    ssm_k<<<dim3(DI / 256, TOKENS), 256, 0, stream>>>(
        ssm_state, A_log, D_param, dt_proj_b, prj, dt, 1, 0, u,
        res, 1, 0, z, probe);
    {
      GemmP p{};
      p.A = z; p.lda = DI; p.a_ws = 1;
      p.B = down_proj; p.B2 = nullptr;
      p.C = oac; p.C2 = nullptr;
      p.ldb = DM; p.ldc = DM;
      p.ksteps = 10; p.nx_half = 1 << 30; p.atomic = 1; p.cstride = 0;
      p.probe = probe;
      gemm_k<<<dim3(DM / 64, 16), 256, 0, stream>>>(p);
    }
    cvt_k<<<dim3((out_size / 8 + 255) / 256), 256, 0, stream>>>(
        oac, 1, 0, d_out, out_size, probe);
  }
}